// Round 13
// baseline (286.815 us; speedup 1.0000x reference)
//
#include <hip/hip_runtime.h>
#include <hip/hip_fp16.h>

// ---------------------------------------------------------------------------
// GCN encoder, 2 layers, N=100000 D=H=128, E=1.6M.
// Round 13: (a) gemm1 moved off the scan critical path -- p1 is hist-only
//           (wfrag fused in), gemm1 tiles backfill the p3a/p3b dispatches;
//           (b) nontemporal out stores in agg kernels.
// Aggs are at the ~3.36 TB/s random-fetch fabric ceiling (FETCH 1.4x of the
// per-XCD-L2 compulsory floor); build is atomic-free LDS counting sort.
// ws: H | sums | rowstart | dis | ep | hW1 | Wf | tmp (aliased by hW2)
// ---------------------------------------------------------------------------

typedef unsigned int u32;
typedef _Float16 f16;
typedef f16 f16x4 __attribute__((ext_vector_type(4)));
typedef f16 f16x8 __attribute__((ext_vector_type(8)));
typedef float f32x4 __attribute__((ext_vector_type(4)));

__device__ __forceinline__ void st_nt_f2(float* p, float ox, float oy) {
    union { double d; float f[2]; } u;
    u.f[0] = ox; u.f[1] = oy;
    __builtin_nontemporal_store(u.d, (double*)p);
}

// ---- MFMA f16 GEMM body: C[64 x 128] (f16) = A(fp32) @ W (via Wf) ----
__device__ __forceinline__ void gemm_body(const float* __restrict__ A, int lda,
                                          const __half* __restrict__ Wf,
                                          __half* __restrict__ C, int n,
                                          int bid, int t) {
    const int w2 = t >> 6, l = t & 63;
    const int node = bid * 64 + w2 * 16 + (l & 15);
    const int koff = ((l >> 4) & 3) * 4;
    const bool ok = node < n;
    const float* ap = A + (size_t)(ok ? node : 0) * lda;

    f16x8 af[4];
#pragma unroll
    for (int ks = 0; ks < 4; ++ks) {
        float4 a0 = make_float4(0.f, 0.f, 0.f, 0.f), a1 = a0;
        if (ok) {
            a0 = *(const float4*)(ap + ks * 32 + koff);
            a1 = *(const float4*)(ap + ks * 32 + koff + 16);
        }
        f16x8 h;
        h[0] = (f16)a0.x; h[1] = (f16)a0.y; h[2] = (f16)a0.z; h[3] = (f16)a0.w;
        h[4] = (f16)a1.x; h[5] = (f16)a1.y; h[6] = (f16)a1.z; h[7] = (f16)a1.w;
        af[ks] = h;
    }

    f32x4 acc[8];
#pragma unroll
    for (int i = 0; i < 8; ++i) acc[i] = (f32x4){0.f, 0.f, 0.f, 0.f};

#pragma unroll
    for (int ks = 0; ks < 4; ++ks) {
#pragma unroll
        for (int nt = 0; nt < 8; ++nt) {
            f16x8 wf = *(const f16x8*)(Wf + ((size_t)(ks * 8 + nt) * 64 + l) * 8);
            acc[nt] = __builtin_amdgcn_mfma_f32_16x16x32_f16(wf, af[ks], acc[nt], 0, 0, 0);
        }
    }

    if (ok) {
        const int c0 = ((l >> 4) & 3) * 4;
#pragma unroll
        for (int nt = 0; nt < 8; ++nt) {
            union { short4 s4; __half h[4]; } pk;
#pragma unroll
            for (int r2 = 0; r2 < 4; ++r2) pk.h[r2] = __float2half(acc[nt][r2]);
            *(short4*)(C + (size_t)node * 128 + nt * 16 + c0) = pk.s4;
        }
    }
}

// p1: blocks [0,nch) coarse histogram (LDS atomics, dst>>9 buckets);
// blocks [nch, nch+16) pack W0,W1 into MFMA fragment order:
// Wf[sel][(ks*8+nt)*64 + l][j] = W[k(l,j)][nt*16 + (l&15)],
//   k(l,j) = ks*32 + ((l>>4)&3)*4 + (j&3) + 16*(j>>2)
__global__ __launch_bounds__(256) void k_p1(const int* __restrict__ dst,
                                            u32* __restrict__ H,
                                            int e, int NB, int nch,
                                            const float* __restrict__ W0,
                                            const float* __restrict__ W1,
                                            __half* __restrict__ Wf) {
    const int bid = blockIdx.x, t = threadIdx.x;
    if (bid >= nch) {
        int idx = (bid - nch) * 256 + t;          // 0..4095
        const float* W = (idx < 2048) ? W0 : W1;
        int id = idx & 2047;
        int l = id & 63, nt = (id >> 6) & 7, ks = id >> 9;
        int nn = nt * 16 + (l & 15);
        int kb = ks * 32 + ((l >> 4) & 3) * 4;
        union { int4 v; __half h[8]; } pk;
#pragma unroll
        for (int j = 0; j < 8; ++j) {
            int k = kb + (j & 3) + 16 * (j >> 2);
            pk.h[j] = __float2half(W[k * 128 + nn]);
        }
        *(int4*)(Wf + (size_t)idx * 8) = pk.v;
        return;
    }
    __shared__ u32 lcnt[512];
    lcnt[t] = 0; lcnt[t + 256] = 0;
    __syncthreads();
    int i0 = bid * 4096 + t;
#pragma unroll
    for (int u = 0; u < 16; ++u) {
        int i = i0 + u * 256;
        if (i < e) atomicAdd(&lcnt[(u32)dst[i] >> 9], 1u);
    }
    __syncthreads();
    for (int b = t; b < NB; b += 256) H[(size_t)b * nch + bid] = lcnt[b];
}

// ---- scan: per-block exclusive scan + block sums; sums scanned by scan2;
// consumers add sums[idx>>8] inline. ----
__global__ __launch_bounds__(256) void k_scan1(u32* data, u32* sums, int n) {
    __shared__ u32 tmp[256];
    int gid = blockIdx.x * 256 + threadIdx.x;
    u32 v = (gid < n) ? data[gid] : 0;
    tmp[threadIdx.x] = v;
    __syncthreads();
    for (int off = 1; off < 256; off <<= 1) {
        u32 t = (threadIdx.x >= off) ? tmp[threadIdx.x - off] : 0;
        __syncthreads();
        tmp[threadIdx.x] += t;
        __syncthreads();
    }
    if (gid < n) data[gid] = tmp[threadIdx.x] - v;
    if (threadIdx.x == 255) sums[blockIdx.x] = tmp[255];
}

__global__ __launch_bounds__(512) void k_scan2(u32* sums, int nb) {
    __shared__ u32 tmp[512];
    u32 v = (threadIdx.x < nb) ? sums[threadIdx.x] : 0;
    tmp[threadIdx.x] = v;
    __syncthreads();
    for (int off = 1; off < 512; off <<= 1) {
        u32 t = (threadIdx.x >= off) ? tmp[threadIdx.x - off] : 0;
        __syncthreads();
        tmp[threadIdx.x] += t;
        __syncthreads();
    }
    if (threadIdx.x < nb) sums[threadIdx.x] = tmp[threadIdx.x] - v;
}

// phase 2: scatter records into bucket-grouped tmp. base = H'[b][bid]+S.
// record: x = src | (dst&511)<<17 ; y = w bits.
__global__ __launch_bounds__(256) void k_p2(const int* __restrict__ src,
                                            const int* __restrict__ dst,
                                            const float* __restrict__ w,
                                            const u32* __restrict__ H,
                                            const u32* __restrict__ S,
                                            int2* __restrict__ tmp,
                                            int e, int NB, int nch) {
    __shared__ u32 lcnt[512];
    __shared__ u32 lbase[512];
    const int t = threadIdx.x, bid = blockIdx.x;
    lcnt[t] = 0; lcnt[t + 256] = 0;
    __syncthreads();
    for (int b = t; b < NB; b += 256) {
        u32 idx = (u32)b * nch + bid;
        lbase[b] = H[idx] + S[idx >> 8];
    }
    __syncthreads();
    int i0 = bid * 4096 + t;
#pragma unroll
    for (int u = 0; u < 16; ++u) {
        int i = i0 + u * 256;
        if (i < e) {
            int d = dst[i];
            u32 b = (u32)d >> 9;
            u32 lr = atomicAdd(&lcnt[b], 1u);
            tmp[lbase[b] + lr] = make_int2(src[i] | ((d & 511) << 17),
                                           __float_as_int(w[i]));
        }
    }
}

// phase 3a: blocks [0,NB): per-bucket count + fixed-point weighted deg ->
// rowstart, dis. blocks [NB,..): gemm1 tiles (2 per 512-thread block).
__global__ __launch_bounds__(512) void k_p3a(const int2* __restrict__ tmp,
                                             const u32* __restrict__ H,
                                             const u32* __restrict__ S,
                                             int* __restrict__ rowstart,
                                             float* __restrict__ dis,
                                             int e, int n, int NB, int nch,
                                             const float* __restrict__ A, int lda,
                                             const __half* __restrict__ Wf,
                                             __half* __restrict__ C, int tileOff) {
    const int bid = blockIdx.x, t = threadIdx.x;
    if (bid >= NB) {
        int g = (bid - NB) * 2 + (t >> 8) + tileOff;
        gemm_body(A, lda, Wf, C, n, g, t & 255);
        return;
    }
    __shared__ u32 cnt[512];
    __shared__ u32 degx[512];
    __shared__ u32 stmp[512];

    cnt[t] = 0; degx[t] = 0;
    __syncthreads();

    u32 i0 = (u32)bid * nch;
    const int bs = (int)(H[i0] + S[i0 >> 8]);
    u32 i1 = (u32)(bid + 1) * nch;
    const int be = (bid + 1 < NB) ? (int)(H[i1] + S[i1 >> 8]) : e;

    for (int j = bs + t; j < be; j += 512) {
        int2 r = tmp[j];
        u32 low = ((u32)r.x >> 17) & 511u;
        atomicAdd(&cnt[low], 1u);
        atomicAdd(&degx[low], (u32)(__int_as_float(r.y) * 1048576.0f + 0.5f));
    }
    __syncthreads();

    u32 v = cnt[t];
    stmp[t] = v;
    __syncthreads();
    for (int o = 1; o < 512; o <<= 1) {
        u32 x = (t >= o) ? stmp[t - o] : 0u;
        __syncthreads();
        stmp[t] += x;
        __syncthreads();
    }

    const int node = bid * 512 + t;
    if (node < n) {
        rowstart[node] = bs + (int)(stmp[t] - v);
        dis[node] = rsqrtf(1.0f + (float)degx[t] * (1.0f / 1048576.0f));
    }
}

// phase 3b: blocks [0,NB): placement. ep[pos] = (src, w * dis[src]).
// blocks [NB,..): remaining gemm1 tiles.
__global__ __launch_bounds__(512) void k_p3b(const int2* __restrict__ tmp,
                                             const u32* __restrict__ H,
                                             const u32* __restrict__ S,
                                             const int* __restrict__ rowstart,
                                             const float* __restrict__ dis,
                                             int2* __restrict__ ep,
                                             int e, int n, int NB, int nch,
                                             const float* __restrict__ A, int lda,
                                             const __half* __restrict__ Wf,
                                             __half* __restrict__ C, int tileOff) {
    const int bid = blockIdx.x, t = threadIdx.x;
    if (bid >= NB) {
        int g = (bid - NB) * 2 + (t >> 8) + tileOff;
        gemm_body(A, lda, Wf, C, n, g, t & 255);
        return;
    }
    __shared__ u32 cur[512];
    const int node = bid * 512 + t;
    cur[t] = (node < n) ? (u32)rowstart[node] : 0u;
    __syncthreads();

    u32 i0 = (u32)bid * nch;
    const int bs = (int)(H[i0] + S[i0 >> 8]);
    u32 i1 = (u32)(bid + 1) * nch;
    const int be = (bid + 1 < NB) ? (int)(H[i1] + S[i1 >> 8]) : e;

    for (int j = bs + t; j < be; j += 512) {
        int2 r = tmp[j];
        u32 low = ((u32)r.x >> 17) & 511u;
        int s = r.x & 0x1FFFF;
        float wd = __int_as_float(r.y) * dis[s];
        u32 p = atomicAdd(&cur[low], 1u);
        ep[p] = make_int2(s, __float_as_int(wd));
    }
}

// ---- agg inner body: acc over one dst row's edges (tiers 16/8/4/1) ----
__device__ __forceinline__ float2 agg_row(const __half* __restrict__ hW, int ldh,
                                          const int2* __restrict__ ep,
                                          int start, int end, int lane,
                                          float2 acc) {
    int j = start;
    for (; j + 15 < end; j += 16) {
        int2 r[16];
        __half2 v[16];
#pragma unroll
        for (int u = 0; u < 16; ++u) r[u] = ep[j + u];
#pragma unroll
        for (int u = 0; u < 16; ++u)
            v[u] = *(const __half2*)(hW + (size_t)r[u].x * ldh + lane * 2);
#pragma unroll
        for (int u = 0; u < 16; ++u) {
            float nm = __int_as_float(r[u].y);
            float2 f = __half22float2(v[u]);
            acc.x += nm * f.x;
            acc.y += nm * f.y;
        }
    }
    for (; j + 7 < end; j += 8) {
        int2 r[8];
        __half2 v[8];
#pragma unroll
        for (int u = 0; u < 8; ++u) r[u] = ep[j + u];
#pragma unroll
        for (int u = 0; u < 8; ++u)
            v[u] = *(const __half2*)(hW + (size_t)r[u].x * ldh + lane * 2);
#pragma unroll
        for (int u = 0; u < 8; ++u) {
            float nm = __int_as_float(r[u].y);
            float2 f = __half22float2(v[u]);
            acc.x += nm * f.x;
            acc.y += nm * f.y;
        }
    }
    for (; j + 3 < end; j += 4) {
        int2 r[4];
        __half2 v[4];
#pragma unroll
        for (int u = 0; u < 4; ++u) r[u] = ep[j + u];
#pragma unroll
        for (int u = 0; u < 4; ++u)
            v[u] = *(const __half2*)(hW + (size_t)r[u].x * ldh + lane * 2);
#pragma unroll
        for (int u = 0; u < 4; ++u) {
            float nm = __int_as_float(r[u].y);
            float2 f = __half22float2(v[u]);
            acc.x += nm * f.x;
            acc.y += nm * f.y;
        }
    }
    for (; j < end; ++j) {
        int2 rec = ep[j];
        float nm = __int_as_float(rec.y);
        float2 v = __half22float2(*(const __half2*)(hW + (size_t)rec.x * ldh + lane * 2));
        acc.x += nm * v.x;
        acc.y += nm * v.y;
    }
    return acc;
}

// fused agg(layer1) + gemm(layer2): block = 16 dst rows (4 waves x 4 rows).
__global__ __launch_bounds__(256) void k_aggemm(const __half* __restrict__ hW1,
                                                const int2* __restrict__ ep,
                                                const int* __restrict__ rowstart,
                                                const float* __restrict__ dis,
                                                const float* __restrict__ bias,
                                                float* __restrict__ outcol,   // stride 256
                                                const __half* __restrict__ Wf2,
                                                __half* __restrict__ hW2,
                                                int n, int e) {
    __shared__ f16 As[16][132];   // padded: spread banks
    const int t = threadIdx.x;
    const int w2 = t >> 6, lane = t & 63;

    float2 b = *(const float2*)(bias + lane * 2);

#pragma unroll
    for (int i = 0; i < 4; ++i) {
        const int lr = w2 * 4 + i;
        const int wid = blockIdx.x * 16 + lr;
        if (wid < n) {
            int start = rowstart[wid];
            int end   = (wid == n - 1) ? e : rowstart[wid + 1];
            start = __builtin_amdgcn_readfirstlane(start);
            end   = __builtin_amdgcn_readfirstlane(end);

            const float dd = dis[wid];
            float2 h = __half22float2(*(const __half2*)(hW1 + (size_t)wid * 128 + lane * 2));
            float2 acc;
            acc.x = dd * h.x;
            acc.y = dd * h.y;
            acc = agg_row(hW1, 128, ep, start, end, lane, acc);

            float ox = fmaxf(dd * acc.x + b.x, 0.f);
            float oy = fmaxf(dd * acc.y + b.y, 0.f);
            st_nt_f2(outcol + (size_t)wid * 256 + lane * 2, ox, oy);
            As[lr][2 * lane]     = (f16)ox;
            As[lr][2 * lane + 1] = (f16)oy;
        } else {
            As[lr][2 * lane]     = (f16)0.f;
            As[lr][2 * lane + 1] = (f16)0.f;
        }
    }
    __syncthreads();

    // layer-2 GEMM for these 16 rows: each wave computes 2 nt column-tiles.
    const int koff = ((lane >> 4) & 3) * 4;
    f32x4 acc2[2];
    acc2[0] = (f32x4){0.f, 0.f, 0.f, 0.f};
    acc2[1] = (f32x4){0.f, 0.f, 0.f, 0.f};

#pragma unroll
    for (int ks = 0; ks < 4; ++ks) {
        f16x4 lo = *(const f16x4*)&As[lane & 15][ks * 32 + koff];
        f16x4 hi = *(const f16x4*)&As[lane & 15][ks * 32 + koff + 16];
        f16x8 af;
        af[0] = lo[0]; af[1] = lo[1]; af[2] = lo[2]; af[3] = lo[3];
        af[4] = hi[0]; af[5] = hi[1]; af[6] = hi[2]; af[7] = hi[3];
#pragma unroll
        for (int q = 0; q < 2; ++q) {
            const int nt = w2 * 2 + q;
            f16x8 wf = *(const f16x8*)(Wf2 + ((size_t)(ks * 8 + nt) * 64 + lane) * 8);
            acc2[q] = __builtin_amdgcn_mfma_f32_16x16x32_f16(wf, af, acc2[q], 0, 0, 0);
        }
    }

    const int node = blockIdx.x * 16 + (lane & 15);
    if (node < n) {
        const int c0 = ((lane >> 4) & 3) * 4;
#pragma unroll
        for (int q = 0; q < 2; ++q) {
            const int nt = w2 * 2 + q;
            union { short4 s4; __half h[4]; } pk;
#pragma unroll
            for (int r2 = 0; r2 < 4; ++r2) pk.h[r2] = __float2half(acc2[q][r2]);
            *(short4*)(hW2 + (size_t)node * 128 + nt * 16 + c0) = pk.s4;
        }
    }
}

// layer-2 agg: out[d,128..255] = relu( dd*(dd*hW2[d] + sum y_j*hW2[s_j]) + b1 )
__global__ __launch_bounds__(256) void k_agg(const __half* __restrict__ hW,
                                             const int2* __restrict__ ep,
                                             const int* __restrict__ rowstart,
                                             const float* __restrict__ dis,
                                             const float* __restrict__ bias,
                                             float* __restrict__ outcol,  // stride 256
                                             int n, int e) {
    int wid = blockIdx.x * 4 + (threadIdx.x >> 6);
    int lane = threadIdx.x & 63;
    if (wid >= n) return;

    int start = rowstart[wid];
    int end   = (wid == n - 1) ? e : rowstart[wid + 1];
    start = __builtin_amdgcn_readfirstlane(start);
    end   = __builtin_amdgcn_readfirstlane(end);

    const float dd = dis[wid];
    float2 h = __half22float2(*(const __half2*)(hW + (size_t)wid * 128 + lane * 2));
    float2 acc;
    acc.x = dd * h.x;
    acc.y = dd * h.y;
    acc = agg_row(hW, 128, ep, start, end, lane, acc);

    float2 b = *(const float2*)(bias + lane * 2);
    float ox = fmaxf(dd * acc.x + b.x, 0.f);
    float oy = fmaxf(dd * acc.y + b.y, 0.f);
    st_nt_f2(outcol + (size_t)wid * 256 + lane * 2, ox, oy);
}

extern "C" void kernel_launch(void* const* d_in, const int* in_sizes, int n_in,
                              void* d_out, int out_size, void* d_ws, size_t ws_size,
                              hipStream_t stream) {
    const float* x  = (const float*)d_in[0];
    const float* ew = (const float*)d_in[1];
    const float* W0 = (const float*)d_in[2];
    const float* b0 = (const float*)d_in[3];
    const float* W1 = (const float*)d_in[4];
    const float* b1 = (const float*)d_in[5];
    const int*   ei = (const int*)d_in[6];

    const int N = in_sizes[0] / 128;
    const int E = in_sizes[1];
    const int* src = ei;
    const int* dst = ei + E;
    float* out = (float*)d_out;   // [N, 256]

    const int NB  = (N + 511) >> 9;          // 196 coarse buckets
    const int nch = (E + 4095) >> 12;        // 391 phase blocks
    const int scanN = NB * nch;              // 76636
    const int scanB = (scanN + 255) / 256;   // 300
    const int gT = (N + 63) / 64;            // gemm1 tiles (1563)
    const int tilesA = ((gT + 1) / 2 + 1) & ~1;   // even split for p3a (782)
    const int blocksA = tilesA / 2;
    const int tilesB = gT - tilesA;               // 781
    const int blocksB = (tilesB + 1) / 2;
    const int gF = (N + 15) / 16;            // fused agg+gemm blocks
    const int gA = (N + 3) / 4;

    // ws layout (4B words; int2 regions 8B-aligned)
    const size_t Hsz  = (size_t)((scanN + 1) & ~1);
    const size_t Npad = (size_t)((N + 1) & ~1);
    u32*   H        = (u32*)d_ws;
    u32*   sums     = H + Hsz;               // 512
    int*   rowstart = (int*)(sums + 512);
    float* dis      = (float*)(rowstart + Npad);
    int2*  ep       = (int2*)(dis + Npad);           // E records
    __half* hW1     = (__half*)(ep + E);             // N*128 halves
    __half* Wf      = hW1 + (size_t)N * 128;         // 32768 halves
    int2*  tmp      = (int2*)(Wf + 32768);           // E records (dead after p3b)
    __half* hW2     = (__half*)tmp;                  // N*128 halves (aliases tmp)

    // ---- CSR build (atomic-free counting sort); gemm1 hidden in p3a/p3b ----
    k_p1<<<nch + 16, 256, 0, stream>>>(dst, H, E, NB, nch, W0, W1, Wf);
    k_scan1<<<scanB, 256, 0, stream>>>(H, sums, scanN);
    k_scan2<<<1, 512, 0, stream>>>(sums, scanB);
    k_p2<<<nch, 256, 0, stream>>>(src, dst, ew, H, sums, tmp, E, NB, nch);
    k_p3a<<<NB + blocksA, 512, 0, stream>>>(tmp, H, sums, rowstart, dis, E, N, NB, nch,
                                            x, 128, Wf, hW1, 0);
    k_p3b<<<NB + blocksB, 512, 0, stream>>>(tmp, H, sums, rowstart, dis, ep, E, N, NB, nch,
                                            x, 128, Wf, hW1, tilesA);

    // ---- layer 1 agg + layer 2 gemm (fused) ----
    k_aggemm<<<gF, 256, 0, stream>>>(hW1, ep, rowstart, dis, b0, out,
                                     Wf + 16384, hW2, N, E);

    // ---- layer 2 agg ----
    k_agg<<<gA, 256, 0, stream>>>(hW2, ep, rowstart, dis, b1, out + 128, N, E);
}

// Round 14
// 272.317 us; speedup vs baseline: 1.0532x; 1.0532x over previous
//
#include <hip/hip_runtime.h>
#include <hip/hip_fp16.h>

// ---------------------------------------------------------------------------
// GCN encoder, 2 layers, N=100000 D=H=128, E=1.6M.
// Round 14: round 13 minus nontemporal stores (NT writes congested the
// fabric and cost ~18 us per agg kernel). Keeps: hist-only p1 (wfrag fused),
// gemm1 tiles backfilling p3a/p3b, fused agg1+gemm2, inline-sum scan.
// Aggs are at the ~3.36 TB/s random-fetch fabric ceiling (FETCH 1.4x of the
// per-XCD-L2 compulsory floor); build is atomic-free LDS counting sort.
// ws: H | sums | rowstart | dis | ep | hW1 | Wf | tmp (aliased by hW2)
// ---------------------------------------------------------------------------

typedef unsigned int u32;
typedef _Float16 f16;
typedef f16 f16x4 __attribute__((ext_vector_type(4)));
typedef f16 f16x8 __attribute__((ext_vector_type(8)));
typedef float f32x4 __attribute__((ext_vector_type(4)));

// ---- MFMA f16 GEMM body: C[64 x 128] (f16) = A(fp32) @ W (via Wf) ----
__device__ __forceinline__ void gemm_body(const float* __restrict__ A, int lda,
                                          const __half* __restrict__ Wf,
                                          __half* __restrict__ C, int n,
                                          int bid, int t) {
    const int w2 = t >> 6, l = t & 63;
    const int node = bid * 64 + w2 * 16 + (l & 15);
    const int koff = ((l >> 4) & 3) * 4;
    const bool ok = node < n;
    const float* ap = A + (size_t)(ok ? node : 0) * lda;

    f16x8 af[4];
#pragma unroll
    for (int ks = 0; ks < 4; ++ks) {
        float4 a0 = make_float4(0.f, 0.f, 0.f, 0.f), a1 = a0;
        if (ok) {
            a0 = *(const float4*)(ap + ks * 32 + koff);
            a1 = *(const float4*)(ap + ks * 32 + koff + 16);
        }
        f16x8 h;
        h[0] = (f16)a0.x; h[1] = (f16)a0.y; h[2] = (f16)a0.z; h[3] = (f16)a0.w;
        h[4] = (f16)a1.x; h[5] = (f16)a1.y; h[6] = (f16)a1.z; h[7] = (f16)a1.w;
        af[ks] = h;
    }

    f32x4 acc[8];
#pragma unroll
    for (int i = 0; i < 8; ++i) acc[i] = (f32x4){0.f, 0.f, 0.f, 0.f};

#pragma unroll
    for (int ks = 0; ks < 4; ++ks) {
#pragma unroll
        for (int nt = 0; nt < 8; ++nt) {
            f16x8 wf = *(const f16x8*)(Wf + ((size_t)(ks * 8 + nt) * 64 + l) * 8);
            acc[nt] = __builtin_amdgcn_mfma_f32_16x16x32_f16(wf, af[ks], acc[nt], 0, 0, 0);
        }
    }

    if (ok) {
        const int c0 = ((l >> 4) & 3) * 4;
#pragma unroll
        for (int nt = 0; nt < 8; ++nt) {
            union { short4 s4; __half h[4]; } pk;
#pragma unroll
            for (int r2 = 0; r2 < 4; ++r2) pk.h[r2] = __float2half(acc[nt][r2]);
            *(short4*)(C + (size_t)node * 128 + nt * 16 + c0) = pk.s4;
        }
    }
}

// p1: blocks [0,nch) coarse histogram (LDS atomics, dst>>9 buckets);
// blocks [nch, nch+16) pack W0,W1 into MFMA fragment order:
// Wf[sel][(ks*8+nt)*64 + l][j] = W[k(l,j)][nt*16 + (l&15)],
//   k(l,j) = ks*32 + ((l>>4)&3)*4 + (j&3) + 16*(j>>2)
__global__ __launch_bounds__(256) void k_p1(const int* __restrict__ dst,
                                            u32* __restrict__ H,
                                            int e, int NB, int nch,
                                            const float* __restrict__ W0,
                                            const float* __restrict__ W1,
                                            __half* __restrict__ Wf) {
    const int bid = blockIdx.x, t = threadIdx.x;
    if (bid >= nch) {
        int idx = (bid - nch) * 256 + t;          // 0..4095
        const float* W = (idx < 2048) ? W0 : W1;
        int id = idx & 2047;
        int l = id & 63, nt = (id >> 6) & 7, ks = id >> 9;
        int nn = nt * 16 + (l & 15);
        int kb = ks * 32 + ((l >> 4) & 3) * 4;
        union { int4 v; __half h[8]; } pk;
#pragma unroll
        for (int j = 0; j < 8; ++j) {
            int k = kb + (j & 3) + 16 * (j >> 2);
            pk.h[j] = __float2half(W[k * 128 + nn]);
        }
        *(int4*)(Wf + (size_t)idx * 8) = pk.v;
        return;
    }
    __shared__ u32 lcnt[512];
    lcnt[t] = 0; lcnt[t + 256] = 0;
    __syncthreads();
    int i0 = bid * 4096 + t;
#pragma unroll
    for (int u = 0; u < 16; ++u) {
        int i = i0 + u * 256;
        if (i < e) atomicAdd(&lcnt[(u32)dst[i] >> 9], 1u);
    }
    __syncthreads();
    for (int b = t; b < NB; b += 256) H[(size_t)b * nch + bid] = lcnt[b];
}

// ---- scan: per-block exclusive scan + block sums; sums scanned by scan2;
// consumers add sums[idx>>8] inline. ----
__global__ __launch_bounds__(256) void k_scan1(u32* data, u32* sums, int n) {
    __shared__ u32 tmp[256];
    int gid = blockIdx.x * 256 + threadIdx.x;
    u32 v = (gid < n) ? data[gid] : 0;
    tmp[threadIdx.x] = v;
    __syncthreads();
    for (int off = 1; off < 256; off <<= 1) {
        u32 t = (threadIdx.x >= off) ? tmp[threadIdx.x - off] : 0;
        __syncthreads();
        tmp[threadIdx.x] += t;
        __syncthreads();
    }
    if (gid < n) data[gid] = tmp[threadIdx.x] - v;
    if (threadIdx.x == 255) sums[blockIdx.x] = tmp[255];
}

__global__ __launch_bounds__(512) void k_scan2(u32* sums, int nb) {
    __shared__ u32 tmp[512];
    u32 v = (threadIdx.x < nb) ? sums[threadIdx.x] : 0;
    tmp[threadIdx.x] = v;
    __syncthreads();
    for (int off = 1; off < 512; off <<= 1) {
        u32 t = (threadIdx.x >= off) ? tmp[threadIdx.x - off] : 0;
        __syncthreads();
        tmp[threadIdx.x] += t;
        __syncthreads();
    }
    if (threadIdx.x < nb) sums[threadIdx.x] = tmp[threadIdx.x] - v;
}

// phase 2: scatter records into bucket-grouped tmp. base = H'[b][bid]+S.
// record: x = src | (dst&511)<<17 ; y = w bits.
__global__ __launch_bounds__(256) void k_p2(const int* __restrict__ src,
                                            const int* __restrict__ dst,
                                            const float* __restrict__ w,
                                            const u32* __restrict__ H,
                                            const u32* __restrict__ S,
                                            int2* __restrict__ tmp,
                                            int e, int NB, int nch) {
    __shared__ u32 lcnt[512];
    __shared__ u32 lbase[512];
    const int t = threadIdx.x, bid = blockIdx.x;
    lcnt[t] = 0; lcnt[t + 256] = 0;
    __syncthreads();
    for (int b = t; b < NB; b += 256) {
        u32 idx = (u32)b * nch + bid;
        lbase[b] = H[idx] + S[idx >> 8];
    }
    __syncthreads();
    int i0 = bid * 4096 + t;
#pragma unroll
    for (int u = 0; u < 16; ++u) {
        int i = i0 + u * 256;
        if (i < e) {
            int d = dst[i];
            u32 b = (u32)d >> 9;
            u32 lr = atomicAdd(&lcnt[b], 1u);
            tmp[lbase[b] + lr] = make_int2(src[i] | ((d & 511) << 17),
                                           __float_as_int(w[i]));
        }
    }
}

// phase 3a: blocks [0,NB): per-bucket count + fixed-point weighted deg ->
// rowstart, dis. blocks [NB,..): gemm1 tiles (2 per 512-thread block).
__global__ __launch_bounds__(512) void k_p3a(const int2* __restrict__ tmp,
                                             const u32* __restrict__ H,
                                             const u32* __restrict__ S,
                                             int* __restrict__ rowstart,
                                             float* __restrict__ dis,
                                             int e, int n, int NB, int nch,
                                             const float* __restrict__ A, int lda,
                                             const __half* __restrict__ Wf,
                                             __half* __restrict__ C, int tileOff) {
    const int bid = blockIdx.x, t = threadIdx.x;
    if (bid >= NB) {
        int g = (bid - NB) * 2 + (t >> 8) + tileOff;
        gemm_body(A, lda, Wf, C, n, g, t & 255);
        return;
    }
    __shared__ u32 cnt[512];
    __shared__ u32 degx[512];
    __shared__ u32 stmp[512];

    cnt[t] = 0; degx[t] = 0;
    __syncthreads();

    u32 i0 = (u32)bid * nch;
    const int bs = (int)(H[i0] + S[i0 >> 8]);
    u32 i1 = (u32)(bid + 1) * nch;
    const int be = (bid + 1 < NB) ? (int)(H[i1] + S[i1 >> 8]) : e;

    for (int j = bs + t; j < be; j += 512) {
        int2 r = tmp[j];
        u32 low = ((u32)r.x >> 17) & 511u;
        atomicAdd(&cnt[low], 1u);
        atomicAdd(&degx[low], (u32)(__int_as_float(r.y) * 1048576.0f + 0.5f));
    }
    __syncthreads();

    u32 v = cnt[t];
    stmp[t] = v;
    __syncthreads();
    for (int o = 1; o < 512; o <<= 1) {
        u32 x = (t >= o) ? stmp[t - o] : 0u;
        __syncthreads();
        stmp[t] += x;
        __syncthreads();
    }

    const int node = bid * 512 + t;
    if (node < n) {
        rowstart[node] = bs + (int)(stmp[t] - v);
        dis[node] = rsqrtf(1.0f + (float)degx[t] * (1.0f / 1048576.0f));
    }
}

// phase 3b: blocks [0,NB): placement. ep[pos] = (src, w * dis[src]).
// blocks [NB,..): remaining gemm1 tiles.
__global__ __launch_bounds__(512) void k_p3b(const int2* __restrict__ tmp,
                                             const u32* __restrict__ H,
                                             const u32* __restrict__ S,
                                             const int* __restrict__ rowstart,
                                             const float* __restrict__ dis,
                                             int2* __restrict__ ep,
                                             int e, int n, int NB, int nch,
                                             const float* __restrict__ A, int lda,
                                             const __half* __restrict__ Wf,
                                             __half* __restrict__ C, int tileOff) {
    const int bid = blockIdx.x, t = threadIdx.x;
    if (bid >= NB) {
        int g = (bid - NB) * 2 + (t >> 8) + tileOff;
        gemm_body(A, lda, Wf, C, n, g, t & 255);
        return;
    }
    __shared__ u32 cur[512];
    const int node = bid * 512 + t;
    cur[t] = (node < n) ? (u32)rowstart[node] : 0u;
    __syncthreads();

    u32 i0 = (u32)bid * nch;
    const int bs = (int)(H[i0] + S[i0 >> 8]);
    u32 i1 = (u32)(bid + 1) * nch;
    const int be = (bid + 1 < NB) ? (int)(H[i1] + S[i1 >> 8]) : e;

    for (int j = bs + t; j < be; j += 512) {
        int2 r = tmp[j];
        u32 low = ((u32)r.x >> 17) & 511u;
        int s = r.x & 0x1FFFF;
        float wd = __int_as_float(r.y) * dis[s];
        u32 p = atomicAdd(&cur[low], 1u);
        ep[p] = make_int2(s, __float_as_int(wd));
    }
}

// ---- agg inner body: acc over one dst row's edges (tiers 16/8/4/1) ----
__device__ __forceinline__ float2 agg_row(const __half* __restrict__ hW, int ldh,
                                          const int2* __restrict__ ep,
                                          int start, int end, int lane,
                                          float2 acc) {
    int j = start;
    for (; j + 15 < end; j += 16) {
        int2 r[16];
        __half2 v[16];
#pragma unroll
        for (int u = 0; u < 16; ++u) r[u] = ep[j + u];
#pragma unroll
        for (int u = 0; u < 16; ++u)
            v[u] = *(const __half2*)(hW + (size_t)r[u].x * ldh + lane * 2);
#pragma unroll
        for (int u = 0; u < 16; ++u) {
            float nm = __int_as_float(r[u].y);
            float2 f = __half22float2(v[u]);
            acc.x += nm * f.x;
            acc.y += nm * f.y;
        }
    }
    for (; j + 7 < end; j += 8) {
        int2 r[8];
        __half2 v[8];
#pragma unroll
        for (int u = 0; u < 8; ++u) r[u] = ep[j + u];
#pragma unroll
        for (int u = 0; u < 8; ++u)
            v[u] = *(const __half2*)(hW + (size_t)r[u].x * ldh + lane * 2);
#pragma unroll
        for (int u = 0; u < 8; ++u) {
            float nm = __int_as_float(r[u].y);
            float2 f = __half22float2(v[u]);
            acc.x += nm * f.x;
            acc.y += nm * f.y;
        }
    }
    for (; j + 3 < end; j += 4) {
        int2 r[4];
        __half2 v[4];
#pragma unroll
        for (int u = 0; u < 4; ++u) r[u] = ep[j + u];
#pragma unroll
        for (int u = 0; u < 4; ++u)
            v[u] = *(const __half2*)(hW + (size_t)r[u].x * ldh + lane * 2);
#pragma unroll
        for (int u = 0; u < 4; ++u) {
            float nm = __int_as_float(r[u].y);
            float2 f = __half22float2(v[u]);
            acc.x += nm * f.x;
            acc.y += nm * f.y;
        }
    }
    for (; j < end; ++j) {
        int2 rec = ep[j];
        float nm = __int_as_float(rec.y);
        float2 v = __half22float2(*(const __half2*)(hW + (size_t)rec.x * ldh + lane * 2));
        acc.x += nm * v.x;
        acc.y += nm * v.y;
    }
    return acc;
}

// fused agg(layer1) + gemm(layer2): block = 16 dst rows (4 waves x 4 rows).
__global__ __launch_bounds__(256) void k_aggemm(const __half* __restrict__ hW1,
                                                const int2* __restrict__ ep,
                                                const int* __restrict__ rowstart,
                                                const float* __restrict__ dis,
                                                const float* __restrict__ bias,
                                                float* __restrict__ outcol,   // stride 256
                                                const __half* __restrict__ Wf2,
                                                __half* __restrict__ hW2,
                                                int n, int e) {
    __shared__ f16 As[16][132];   // padded: spread banks
    const int t = threadIdx.x;
    const int w2 = t >> 6, lane = t & 63;

    float2 b = *(const float2*)(bias + lane * 2);

#pragma unroll
    for (int i = 0; i < 4; ++i) {
        const int lr = w2 * 4 + i;
        const int wid = blockIdx.x * 16 + lr;
        if (wid < n) {
            int start = rowstart[wid];
            int end   = (wid == n - 1) ? e : rowstart[wid + 1];
            start = __builtin_amdgcn_readfirstlane(start);
            end   = __builtin_amdgcn_readfirstlane(end);

            const float dd = dis[wid];
            float2 h = __half22float2(*(const __half2*)(hW1 + (size_t)wid * 128 + lane * 2));
            float2 acc;
            acc.x = dd * h.x;
            acc.y = dd * h.y;
            acc = agg_row(hW1, 128, ep, start, end, lane, acc);

            float ox = fmaxf(dd * acc.x + b.x, 0.f);
            float oy = fmaxf(dd * acc.y + b.y, 0.f);
            *(float2*)(outcol + (size_t)wid * 256 + lane * 2) = make_float2(ox, oy);
            As[lr][2 * lane]     = (f16)ox;
            As[lr][2 * lane + 1] = (f16)oy;
        } else {
            As[lr][2 * lane]     = (f16)0.f;
            As[lr][2 * lane + 1] = (f16)0.f;
        }
    }
    __syncthreads();

    // layer-2 GEMM for these 16 rows: each wave computes 2 nt column-tiles.
    const int koff = ((lane >> 4) & 3) * 4;
    f32x4 acc2[2];
    acc2[0] = (f32x4){0.f, 0.f, 0.f, 0.f};
    acc2[1] = (f32x4){0.f, 0.f, 0.f, 0.f};

#pragma unroll
    for (int ks = 0; ks < 4; ++ks) {
        f16x4 lo = *(const f16x4*)&As[lane & 15][ks * 32 + koff];
        f16x4 hi = *(const f16x4*)&As[lane & 15][ks * 32 + koff + 16];
        f16x8 af;
        af[0] = lo[0]; af[1] = lo[1]; af[2] = lo[2]; af[3] = lo[3];
        af[4] = hi[0]; af[5] = hi[1]; af[6] = hi[2]; af[7] = hi[3];
#pragma unroll
        for (int q = 0; q < 2; ++q) {
            const int nt = w2 * 2 + q;
            f16x8 wf = *(const f16x8*)(Wf2 + ((size_t)(ks * 8 + nt) * 64 + lane) * 8);
            acc2[q] = __builtin_amdgcn_mfma_f32_16x16x32_f16(wf, af, acc2[q], 0, 0, 0);
        }
    }

    const int node = blockIdx.x * 16 + (lane & 15);
    if (node < n) {
        const int c0 = ((lane >> 4) & 3) * 4;
#pragma unroll
        for (int q = 0; q < 2; ++q) {
            const int nt = w2 * 2 + q;
            union { short4 s4; __half h[4]; } pk;
#pragma unroll
            for (int r2 = 0; r2 < 4; ++r2) pk.h[r2] = __float2half(acc2[q][r2]);
            *(short4*)(hW2 + (size_t)node * 128 + nt * 16 + c0) = pk.s4;
        }
    }
}

// layer-2 agg: out[d,128..255] = relu( dd*(dd*hW2[d] + sum y_j*hW2[s_j]) + b1 )
__global__ __launch_bounds__(256) void k_agg(const __half* __restrict__ hW,
                                             const int2* __restrict__ ep,
                                             const int* __restrict__ rowstart,
                                             const float* __restrict__ dis,
                                             const float* __restrict__ bias,
                                             float* __restrict__ outcol,  // stride 256
                                             int n, int e) {
    int wid = blockIdx.x * 4 + (threadIdx.x >> 6);
    int lane = threadIdx.x & 63;
    if (wid >= n) return;

    int start = rowstart[wid];
    int end   = (wid == n - 1) ? e : rowstart[wid + 1];
    start = __builtin_amdgcn_readfirstlane(start);
    end   = __builtin_amdgcn_readfirstlane(end);

    const float dd = dis[wid];
    float2 h = __half22float2(*(const __half2*)(hW + (size_t)wid * 128 + lane * 2));
    float2 acc;
    acc.x = dd * h.x;
    acc.y = dd * h.y;
    acc = agg_row(hW, 128, ep, start, end, lane, acc);

    float2 b = *(const float2*)(bias + lane * 2);
    float2 o;
    o.x = fmaxf(dd * acc.x + b.x, 0.f);
    o.y = fmaxf(dd * acc.y + b.y, 0.f);
    *(float2*)(outcol + (size_t)wid * 256 + lane * 2) = o;
}

extern "C" void kernel_launch(void* const* d_in, const int* in_sizes, int n_in,
                              void* d_out, int out_size, void* d_ws, size_t ws_size,
                              hipStream_t stream) {
    const float* x  = (const float*)d_in[0];
    const float* ew = (const float*)d_in[1];
    const float* W0 = (const float*)d_in[2];
    const float* b0 = (const float*)d_in[3];
    const float* W1 = (const float*)d_in[4];
    const float* b1 = (const float*)d_in[5];
    const int*   ei = (const int*)d_in[6];

    const int N = in_sizes[0] / 128;
    const int E = in_sizes[1];
    const int* src = ei;
    const int* dst = ei + E;
    float* out = (float*)d_out;   // [N, 256]

    const int NB  = (N + 511) >> 9;          // 196 coarse buckets
    const int nch = (E + 4095) >> 12;        // 391 phase blocks
    const int scanN = NB * nch;              // 76636
    const int scanB = (scanN + 255) / 256;   // 300
    const int gT = (N + 63) / 64;            // gemm1 tiles (1563)
    const int tilesA = ((gT + 1) / 2 + 1) & ~1;   // even split for p3a (782)
    const int blocksA = tilesA / 2;
    const int tilesB = gT - tilesA;               // 781
    const int blocksB = (tilesB + 1) / 2;
    const int gF = (N + 15) / 16;            // fused agg+gemm blocks
    const int gA = (N + 3) / 4;

    // ws layout (4B words; int2 regions 8B-aligned)
    const size_t Hsz  = (size_t)((scanN + 1) & ~1);
    const size_t Npad = (size_t)((N + 1) & ~1);
    u32*   H        = (u32*)d_ws;
    u32*   sums     = H + Hsz;               // 512
    int*   rowstart = (int*)(sums + 512);
    float* dis      = (float*)(rowstart + Npad);
    int2*  ep       = (int2*)(dis + Npad);           // E records
    __half* hW1     = (__half*)(ep + E);             // N*128 halves
    __half* Wf      = hW1 + (size_t)N * 128;         // 32768 halves
    int2*  tmp      = (int2*)(Wf + 32768);           // E records (dead after p3b)
    __half* hW2     = (__half*)tmp;                  // N*128 halves (aliases tmp)

    // ---- CSR build (atomic-free counting sort); gemm1 hidden in p3a/p3b ----
    k_p1<<<nch + 16, 256, 0, stream>>>(dst, H, E, NB, nch, W0, W1, Wf);
    k_scan1<<<scanB, 256, 0, stream>>>(H, sums, scanN);
    k_scan2<<<1, 512, 0, stream>>>(sums, scanB);
    k_p2<<<nch, 256, 0, stream>>>(src, dst, ew, H, sums, tmp, E, NB, nch);
    k_p3a<<<NB + blocksA, 512, 0, stream>>>(tmp, H, sums, rowstart, dis, E, N, NB, nch,
                                            x, 128, Wf, hW1, 0);
    k_p3b<<<NB + blocksB, 512, 0, stream>>>(tmp, H, sums, rowstart, dis, ep, E, N, NB, nch,
                                            x, 128, Wf, hW1, tilesA);

    // ---- layer 1 agg + layer 2 gemm (fused) ----
    k_aggemm<<<gF, 256, 0, stream>>>(hW1, ep, rowstart, dis, b0, out,
                                     Wf + 16384, hW2, N, E);

    // ---- layer 2 agg ----
    k_agg<<<gA, 256, 0, stream>>>(hW2, ep, rowstart, dis, b1, out + 128, N, E);
}

// Round 15
// 259.758 us; speedup vs baseline: 1.1042x; 1.0483x over previous
//
#include <hip/hip_runtime.h>
#include <hip/hip_fp16.h>

// ---------------------------------------------------------------------------
// GCN encoder, 2 layers, N=100000 D=H=128, E=1.6M.
// Round 15: revert to the round-12 best configuration (260 us). R13/R14
// established: NT stores -18us/kernel regression; gemm backfill in p3a/p3b
// -12us regression vs backfill in p1. This is the measured-best arrangement:
//   wfrag -> p1gemm(hist+gemm1) -> scan1 -> scan2 -> p2 -> p3a -> p3b
//   -> aggemm(agg1+gemm2 fused) -> agg2.
// Aggs are pinned at the ~3.36-3.9 TB/s random-gather fabric ceiling
// (invariant across 6 structural variants); FETCH within 1.4x of the
// per-XCD compulsory floor; build is atomic-free LDS counting sort.
// ws: H | sums | rowstart | dis | ep | hW1 | Wf | tmp (aliased by hW2)
// ---------------------------------------------------------------------------

typedef unsigned int u32;
typedef _Float16 f16;
typedef f16 f16x4 __attribute__((ext_vector_type(4)));
typedef f16 f16x8 __attribute__((ext_vector_type(8)));
typedef float f32x4 __attribute__((ext_vector_type(4)));

// Pack W0,W1 (fp32 [128][128]) into MFMA fragment order:
// Wf[sel][(ks*8+nt)*64 + l][j] = W[k(l,j)][nt*16 + (l&15)],
//   k(l,j) = ks*32 + ((l>>4)&3)*4 + (j&3) + 16*(j>>2)
__global__ __launch_bounds__(256) void k_wfrag(const float* __restrict__ W0,
                                               const float* __restrict__ W1,
                                               __half* __restrict__ Wf) {
    int idx = blockIdx.x * 256 + threadIdx.x;     // 0..4095
    const float* W = (idx < 2048) ? W0 : W1;
    int id = idx & 2047;
    int l = id & 63, nt = (id >> 6) & 7, ks = id >> 9;
    int nn = nt * 16 + (l & 15);
    int kb = ks * 32 + ((l >> 4) & 3) * 4;
    union { int4 v; __half h[8]; } pk;
#pragma unroll
    for (int j = 0; j < 8; ++j) {
        int k = kb + (j & 3) + 16 * (j >> 2);
        pk.h[j] = __float2half(W[k * 128 + nn]);
    }
    *(int4*)(Wf + (size_t)idx * 8) = pk.v;
}

// ---- MFMA f16 GEMM body: C[64 x 128] (f16) = A(fp32) @ W (via Wf) ----
__device__ __forceinline__ void gemm_body(const float* __restrict__ A, int lda,
                                          const __half* __restrict__ Wf,
                                          __half* __restrict__ C, int n,
                                          int bid, int t) {
    const int w2 = t >> 6, l = t & 63;
    const int node = bid * 64 + w2 * 16 + (l & 15);
    const int koff = ((l >> 4) & 3) * 4;
    const bool ok = node < n;
    const float* ap = A + (size_t)(ok ? node : 0) * lda;

    f16x8 af[4];
#pragma unroll
    for (int ks = 0; ks < 4; ++ks) {
        float4 a0 = make_float4(0.f, 0.f, 0.f, 0.f), a1 = a0;
        if (ok) {
            a0 = *(const float4*)(ap + ks * 32 + koff);
            a1 = *(const float4*)(ap + ks * 32 + koff + 16);
        }
        f16x8 h;
        h[0] = (f16)a0.x; h[1] = (f16)a0.y; h[2] = (f16)a0.z; h[3] = (f16)a0.w;
        h[4] = (f16)a1.x; h[5] = (f16)a1.y; h[6] = (f16)a1.z; h[7] = (f16)a1.w;
        af[ks] = h;
    }

    f32x4 acc[8];
#pragma unroll
    for (int i = 0; i < 8; ++i) acc[i] = (f32x4){0.f, 0.f, 0.f, 0.f};

#pragma unroll
    for (int ks = 0; ks < 4; ++ks) {
#pragma unroll
        for (int nt = 0; nt < 8; ++nt) {
            f16x8 wf = *(const f16x8*)(Wf + ((size_t)(ks * 8 + nt) * 64 + l) * 8);
            acc[nt] = __builtin_amdgcn_mfma_f32_16x16x32_f16(wf, af[ks], acc[nt], 0, 0, 0);
        }
    }

    if (ok) {
        const int c0 = ((l >> 4) & 3) * 4;
#pragma unroll
        for (int nt = 0; nt < 8; ++nt) {
            union { short4 s4; __half h[4]; } pk;
#pragma unroll
            for (int r2 = 0; r2 < 4; ++r2) pk.h[r2] = __float2half(acc[nt][r2]);
            *(short4*)(C + (size_t)node * 128 + nt * 16 + c0) = pk.s4;
        }
    }
}

// fused: blocks [0,nch) coarse histogram (LDS atomics, dst>>9 buckets);
// blocks [nch, nch+gT) gemm1 tiles (hW1, independent of CSR).
__global__ __launch_bounds__(256) void k_p1gemm(const int* __restrict__ dst,
                                                u32* __restrict__ H,
                                                int e, int NB, int nch,
                                                const float* __restrict__ A, int lda,
                                                const __half* __restrict__ Wf,
                                                __half* __restrict__ C, int n) {
    const int bid = blockIdx.x, t = threadIdx.x;
    if (bid >= nch) {
        gemm_body(A, lda, Wf, C, n, bid - nch, t);
        return;
    }
    __shared__ u32 lcnt[512];
    lcnt[t] = 0; lcnt[t + 256] = 0;
    __syncthreads();
    int i0 = bid * 4096 + t;
#pragma unroll
    for (int u = 0; u < 16; ++u) {
        int i = i0 + u * 256;
        if (i < e) atomicAdd(&lcnt[(u32)dst[i] >> 9], 1u);
    }
    __syncthreads();
    for (int b = t; b < NB; b += 256) H[(size_t)b * nch + bid] = lcnt[b];
}

// ---- scan: per-block exclusive scan + block sums; sums scanned by scan2;
// consumers add sums[idx>>8] inline (no scan3 pass). ----
__global__ __launch_bounds__(256) void k_scan1(u32* data, u32* sums, int n) {
    __shared__ u32 tmp[256];
    int gid = blockIdx.x * 256 + threadIdx.x;
    u32 v = (gid < n) ? data[gid] : 0;
    tmp[threadIdx.x] = v;
    __syncthreads();
    for (int off = 1; off < 256; off <<= 1) {
        u32 t = (threadIdx.x >= off) ? tmp[threadIdx.x - off] : 0;
        __syncthreads();
        tmp[threadIdx.x] += t;
        __syncthreads();
    }
    if (gid < n) data[gid] = tmp[threadIdx.x] - v;
    if (threadIdx.x == 255) sums[blockIdx.x] = tmp[255];
}

__global__ __launch_bounds__(512) void k_scan2(u32* sums, int nb) {
    __shared__ u32 tmp[512];
    u32 v = (threadIdx.x < nb) ? sums[threadIdx.x] : 0;
    tmp[threadIdx.x] = v;
    __syncthreads();
    for (int off = 1; off < 512; off <<= 1) {
        u32 t = (threadIdx.x >= off) ? tmp[threadIdx.x - off] : 0;
        __syncthreads();
        tmp[threadIdx.x] += t;
        __syncthreads();
    }
    if (threadIdx.x < nb) sums[threadIdx.x] = tmp[threadIdx.x] - v;
}

// phase 2: scatter records into bucket-grouped tmp. base = H'[b][bid]+S.
// record: x = src | (dst&511)<<17 ; y = w bits.
__global__ __launch_bounds__(256) void k_p2(const int* __restrict__ src,
                                            const int* __restrict__ dst,
                                            const float* __restrict__ w,
                                            const u32* __restrict__ H,
                                            const u32* __restrict__ S,
                                            int2* __restrict__ tmp,
                                            int e, int NB, int nch) {
    __shared__ u32 lcnt[512];
    __shared__ u32 lbase[512];
    const int t = threadIdx.x, bid = blockIdx.x;
    lcnt[t] = 0; lcnt[t + 256] = 0;
    __syncthreads();
    for (int b = t; b < NB; b += 256) {
        u32 idx = (u32)b * nch + bid;
        lbase[b] = H[idx] + S[idx >> 8];
    }
    __syncthreads();
    int i0 = bid * 4096 + t;
#pragma unroll
    for (int u = 0; u < 16; ++u) {
        int i = i0 + u * 256;
        if (i < e) {
            int d = dst[i];
            u32 b = (u32)d >> 9;
            u32 lr = atomicAdd(&lcnt[b], 1u);
            tmp[lbase[b] + lr] = make_int2(src[i] | ((d & 511) << 17),
                                           __float_as_int(w[i]));
        }
    }
}

// phase 3a: per-bucket count + fixed-point weighted deg -> rowstart, dis.
__global__ __launch_bounds__(512) void k_p3a(const int2* __restrict__ tmp,
                                             const u32* __restrict__ H,
                                             const u32* __restrict__ S,
                                             int* __restrict__ rowstart,
                                             float* __restrict__ dis,
                                             int e, int n, int NB, int nch) {
    const int bid = blockIdx.x, t = threadIdx.x;
    __shared__ u32 cnt[512];
    __shared__ u32 degx[512];
    __shared__ u32 stmp[512];

    cnt[t] = 0; degx[t] = 0;
    __syncthreads();

    u32 i0 = (u32)bid * nch;
    const int bs = (int)(H[i0] + S[i0 >> 8]);
    u32 i1 = (u32)(bid + 1) * nch;
    const int be = (bid + 1 < NB) ? (int)(H[i1] + S[i1 >> 8]) : e;

    for (int j = bs + t; j < be; j += 512) {
        int2 r = tmp[j];
        u32 low = ((u32)r.x >> 17) & 511u;
        atomicAdd(&cnt[low], 1u);
        atomicAdd(&degx[low], (u32)(__int_as_float(r.y) * 1048576.0f + 0.5f));
    }
    __syncthreads();

    u32 v = cnt[t];
    stmp[t] = v;
    __syncthreads();
    for (int o = 1; o < 512; o <<= 1) {
        u32 x = (t >= o) ? stmp[t - o] : 0u;
        __syncthreads();
        stmp[t] += x;
        __syncthreads();
    }

    const int node = bid * 512 + t;
    if (node < n) {
        rowstart[node] = bs + (int)(stmp[t] - v);
        dis[node] = rsqrtf(1.0f + (float)degx[t] * (1.0f / 1048576.0f));
    }
}

// phase 3b: placement. ep[pos] = (src, w * dis[src]); LDS cursors from rowstart.
__global__ __launch_bounds__(512) void k_p3b(const int2* __restrict__ tmp,
                                             const u32* __restrict__ H,
                                             const u32* __restrict__ S,
                                             const int* __restrict__ rowstart,
                                             const float* __restrict__ dis,
                                             int2* __restrict__ ep,
                                             int e, int n, int NB, int nch) {
    const int bid = blockIdx.x, t = threadIdx.x;
    __shared__ u32 cur[512];
    const int node = bid * 512 + t;
    cur[t] = (node < n) ? (u32)rowstart[node] : 0u;
    __syncthreads();

    u32 i0 = (u32)bid * nch;
    const int bs = (int)(H[i0] + S[i0 >> 8]);
    u32 i1 = (u32)(bid + 1) * nch;
    const int be = (bid + 1 < NB) ? (int)(H[i1] + S[i1 >> 8]) : e;

    for (int j = bs + t; j < be; j += 512) {
        int2 r = tmp[j];
        u32 low = ((u32)r.x >> 17) & 511u;
        int s = r.x & 0x1FFFF;
        float wd = __int_as_float(r.y) * dis[s];
        u32 p = atomicAdd(&cur[low], 1u);
        ep[p] = make_int2(s, __float_as_int(wd));
    }
}

// ---- agg inner body: acc over one dst row's edges (tiers 16/8/4/1) ----
__device__ __forceinline__ float2 agg_row(const __half* __restrict__ hW, int ldh,
                                          const int2* __restrict__ ep,
                                          int start, int end, int lane,
                                          float2 acc) {
    int j = start;
    for (; j + 15 < end; j += 16) {
        int2 r[16];
        __half2 v[16];
#pragma unroll
        for (int u = 0; u < 16; ++u) r[u] = ep[j + u];
#pragma unroll
        for (int u = 0; u < 16; ++u)
            v[u] = *(const __half2*)(hW + (size_t)r[u].x * ldh + lane * 2);
#pragma unroll
        for (int u = 0; u < 16; ++u) {
            float nm = __int_as_float(r[u].y);
            float2 f = __half22float2(v[u]);
            acc.x += nm * f.x;
            acc.y += nm * f.y;
        }
    }
    for (; j + 7 < end; j += 8) {
        int2 r[8];
        __half2 v[8];
#pragma unroll
        for (int u = 0; u < 8; ++u) r[u] = ep[j + u];
#pragma unroll
        for (int u = 0; u < 8; ++u)
            v[u] = *(const __half2*)(hW + (size_t)r[u].x * ldh + lane * 2);
#pragma unroll
        for (int u = 0; u < 8; ++u) {
            float nm = __int_as_float(r[u].y);
            float2 f = __half22float2(v[u]);
            acc.x += nm * f.x;
            acc.y += nm * f.y;
        }
    }
    for (; j + 3 < end; j += 4) {
        int2 r[4];
        __half2 v[4];
#pragma unroll
        for (int u = 0; u < 4; ++u) r[u] = ep[j + u];
#pragma unroll
        for (int u = 0; u < 4; ++u)
            v[u] = *(const __half2*)(hW + (size_t)r[u].x * ldh + lane * 2);
#pragma unroll
        for (int u = 0; u < 4; ++u) {
            float nm = __int_as_float(r[u].y);
            float2 f = __half22float2(v[u]);
            acc.x += nm * f.x;
            acc.y += nm * f.y;
        }
    }
    for (; j < end; ++j) {
        int2 rec = ep[j];
        float nm = __int_as_float(rec.y);
        float2 v = __half22float2(*(const __half2*)(hW + (size_t)rec.x * ldh + lane * 2));
        acc.x += nm * v.x;
        acc.y += nm * v.y;
    }
    return acc;
}

// fused agg(layer1) + gemm(layer2): block = 16 dst rows (4 waves x 4 rows).
// Per row: o = relu(dd*(dd*hW1[d] + sum y_j*hW1[s_j]) + b0); store out fp32;
// stage o as f16 in LDS. Then 16x128 @ W1 via MFMA -> hW2 (f16).
__global__ __launch_bounds__(256) void k_aggemm(const __half* __restrict__ hW1,
                                                const int2* __restrict__ ep,
                                                const int* __restrict__ rowstart,
                                                const float* __restrict__ dis,
                                                const float* __restrict__ bias,
                                                float* __restrict__ outcol,   // stride 256
                                                const __half* __restrict__ Wf2,
                                                __half* __restrict__ hW2,
                                                int n, int e) {
    __shared__ f16 As[16][132];   // padded: spread banks
    const int t = threadIdx.x;
    const int w2 = t >> 6, lane = t & 63;

    float2 b = *(const float2*)(bias + lane * 2);

#pragma unroll
    for (int i = 0; i < 4; ++i) {
        const int lr = w2 * 4 + i;
        const int wid = blockIdx.x * 16 + lr;
        if (wid < n) {
            int start = rowstart[wid];
            int end   = (wid == n - 1) ? e : rowstart[wid + 1];
            start = __builtin_amdgcn_readfirstlane(start);
            end   = __builtin_amdgcn_readfirstlane(end);

            const float dd = dis[wid];
            float2 h = __half22float2(*(const __half2*)(hW1 + (size_t)wid * 128 + lane * 2));
            float2 acc;
            acc.x = dd * h.x;
            acc.y = dd * h.y;
            acc = agg_row(hW1, 128, ep, start, end, lane, acc);

            float ox = fmaxf(dd * acc.x + b.x, 0.f);
            float oy = fmaxf(dd * acc.y + b.y, 0.f);
            *(float2*)(outcol + (size_t)wid * 256 + lane * 2) = make_float2(ox, oy);
            As[lr][2 * lane]     = (f16)ox;
            As[lr][2 * lane + 1] = (f16)oy;
        } else {
            As[lr][2 * lane]     = (f16)0.f;
            As[lr][2 * lane + 1] = (f16)0.f;
        }
    }
    __syncthreads();

    // layer-2 GEMM for these 16 rows: each wave computes 2 nt column-tiles.
    const int koff = ((lane >> 4) & 3) * 4;
    f32x4 acc2[2];
    acc2[0] = (f32x4){0.f, 0.f, 0.f, 0.f};
    acc2[1] = (f32x4){0.f, 0.f, 0.f, 0.f};

#pragma unroll
    for (int ks = 0; ks < 4; ++ks) {
        f16x4 lo = *(const f16x4*)&As[lane & 15][ks * 32 + koff];
        f16x4 hi = *(const f16x4*)&As[lane & 15][ks * 32 + koff + 16];
        f16x8 af;
        af[0] = lo[0]; af[1] = lo[1]; af[2] = lo[2]; af[3] = lo[3];
        af[4] = hi[0]; af[5] = hi[1]; af[6] = hi[2]; af[7] = hi[3];
#pragma unroll
        for (int q = 0; q < 2; ++q) {
            const int nt = w2 * 2 + q;
            f16x8 wf = *(const f16x8*)(Wf2 + ((size_t)(ks * 8 + nt) * 64 + lane) * 8);
            acc2[q] = __builtin_amdgcn_mfma_f32_16x16x32_f16(wf, af, acc2[q], 0, 0, 0);
        }
    }

    const int node = blockIdx.x * 16 + (lane & 15);
    if (node < n) {
        const int c0 = ((lane >> 4) & 3) * 4;
#pragma unroll
        for (int q = 0; q < 2; ++q) {
            const int nt = w2 * 2 + q;
            union { short4 s4; __half h[4]; } pk;
#pragma unroll
            for (int r2 = 0; r2 < 4; ++r2) pk.h[r2] = __float2half(acc2[q][r2]);
            *(short4*)(hW2 + (size_t)node * 128 + nt * 16 + c0) = pk.s4;
        }
    }
}

// layer-2 agg: out[d,128..255] = relu( dd*(dd*hW2[d] + sum y_j*hW2[s_j]) + b1 )
__global__ __launch_bounds__(256) void k_agg(const __half* __restrict__ hW,
                                             const int2* __restrict__ ep,
                                             const int* __restrict__ rowstart,
                                             const float* __restrict__ dis,
                                             const float* __restrict__ bias,
                                             float* __restrict__ outcol,  // stride 256
                                             int n, int e) {
    int wid = blockIdx.x * 4 + (threadIdx.x >> 6);
    int lane = threadIdx.x & 63;
    if (wid >= n) return;

    int start = rowstart[wid];
    int end   = (wid == n - 1) ? e : rowstart[wid + 1];
    start = __builtin_amdgcn_readfirstlane(start);
    end   = __builtin_amdgcn_readfirstlane(end);

    const float dd = dis[wid];
    float2 h = __half22float2(*(const __half2*)(hW + (size_t)wid * 128 + lane * 2));
    float2 acc;
    acc.x = dd * h.x;
    acc.y = dd * h.y;
    acc = agg_row(hW, 128, ep, start, end, lane, acc);

    float2 b = *(const float2*)(bias + lane * 2);
    float2 o;
    o.x = fmaxf(dd * acc.x + b.x, 0.f);
    o.y = fmaxf(dd * acc.y + b.y, 0.f);
    *(float2*)(outcol + (size_t)wid * 256 + lane * 2) = o;
}

extern "C" void kernel_launch(void* const* d_in, const int* in_sizes, int n_in,
                              void* d_out, int out_size, void* d_ws, size_t ws_size,
                              hipStream_t stream) {
    const float* x  = (const float*)d_in[0];
    const float* ew = (const float*)d_in[1];
    const float* W0 = (const float*)d_in[2];
    const float* b0 = (const float*)d_in[3];
    const float* W1 = (const float*)d_in[4];
    const float* b1 = (const float*)d_in[5];
    const int*   ei = (const int*)d_in[6];

    const int N = in_sizes[0] / 128;
    const int E = in_sizes[1];
    const int* src = ei;
    const int* dst = ei + E;
    float* out = (float*)d_out;   // [N, 256]

    const int NB  = (N + 511) >> 9;          // 196 coarse buckets
    const int nch = (E + 4095) >> 12;        // 391 phase blocks
    const int scanN = NB * nch;              // 76636
    const int scanB = (scanN + 255) / 256;   // 300
    const int gT = (N + 63) / 64;            // gemm1 tiles
    const int gF = (N + 15) / 16;            // fused agg+gemm blocks
    const int gA = (N + 3) / 4;

    // ws layout (4B words; int2 regions 8B-aligned)
    const size_t Hsz  = (size_t)((scanN + 1) & ~1);
    const size_t Npad = (size_t)((N + 1) & ~1);
    u32*   H        = (u32*)d_ws;
    u32*   sums     = H + Hsz;               // 512
    int*   rowstart = (int*)(sums + 512);
    float* dis      = (float*)(rowstart + Npad);
    int2*  ep       = (int2*)(dis + Npad);           // E records
    __half* hW1     = (__half*)(ep + E);             // N*128 halves
    __half* Wf      = hW1 + (size_t)N * 128;         // 32768 halves
    int2*  tmp      = (int2*)(Wf + 32768);           // E records (dead after p3b)
    __half* hW2     = (__half*)tmp;                  // N*128 halves (aliases tmp)

    // ---- CSR build (atomic-free counting sort); gemm1 fused under p1 ----
    k_wfrag<<<16, 256, 0, stream>>>(W0, W1, Wf);
    k_p1gemm<<<nch + gT, 256, 0, stream>>>(dst, H, E, NB, nch, x, 128, Wf, hW1, N);
    k_scan1<<<scanB, 256, 0, stream>>>(H, sums, scanN);
    k_scan2<<<1, 512, 0, stream>>>(sums, scanB);
    k_p2<<<nch, 256, 0, stream>>>(src, dst, ew, H, sums, tmp, E, NB, nch);
    k_p3a<<<NB, 512, 0, stream>>>(tmp, H, sums, rowstart, dis, E, N, NB, nch);
    k_p3b<<<NB, 512, 0, stream>>>(tmp, H, sums, rowstart, dis, ep, E, N, NB, nch);

    // ---- layer 1 agg + layer 2 gemm (fused) ----
    k_aggemm<<<gF, 256, 0, stream>>>(hW1, ep, rowstart, dis, b0, out,
                                     Wf + 16384, hW2, N, E);

    // ---- layer 2 agg ----
    k_agg<<<gA, 256, 0, stream>>>(hW2, ep, rowstart, dis, b1, out + 128, N, E);
}